// Round 1
// baseline (741.708 us; speedup 1.0000x reference)
//
#include <hip/hip_runtime.h>
#include <cstddef>

constexpr int B = 2, H = 16, S = 2048, D = 128;
constexpr int BH = B * H;
constexpr int TWOD = 2 * D;          // 256
constexpr int QTILE = 128;           // q rows per block: 4 waves x 2 mtiles x 16
constexpr int BC = 32;               // keys per tile
constexpr int NKT = S / BC;          // 64
constexpr float SCALE = 0.08838834764831845f;  // 1/sqrt(128)
constexpr float LAM_INIT = 0.8f;
constexpr float GN_EPS = 1e-5f;

typedef __attribute__((ext_vector_type(8))) short short8;
typedef __attribute__((ext_vector_type(4))) float f32x4;

__device__ __forceinline__ unsigned short f2b(float f) {
  // fp32 -> bf16 round-to-nearest-even
  unsigned int u = __float_as_uint(f);
  u += 0x7fffu + ((u >> 16) & 1u);
  return (unsigned short)(u >> 16);
}

// ---------------- kernel 0: lambda scalar -> wsf[0] ----------------
__global__ void lam_kernel(const float* __restrict__ lq1, const float* __restrict__ lq2,
                           const float* __restrict__ lk1, const float* __restrict__ lk2,
                           float* __restrict__ wsf) {
  __shared__ float r1[128], r2[128];
  int t = threadIdx.x;
  r1[t] = lq1[t] * lk1[t];
  r2[t] = lq2[t] * lk2[t];
  __syncthreads();
  if (t == 0) {
    float s1 = 0.f, s2 = 0.f;
    for (int i = 0; i < 128; ++i) { s1 += r1[i]; s2 += r2[i]; }
    wsf[0] = expf(s1) - expf(s2) + LAM_INIT;
  }
}

// ---------------- kernel 1: v [bh][s][d] fp32 -> vt [bh][d][s] bf16 ----------------
__global__ void vt_kernel(const float* __restrict__ v, unsigned short* __restrict__ vtg) {
  __shared__ float tile[32][132];
  const int bh = blockIdx.y, s0 = blockIdx.x * 32, t = threadIdx.x;
#pragma unroll
  for (int i = 0; i < 4; ++i) {
    int idx = t + i * 256;            // 1024 float4 chunks (32 s x 32 f4)
    int row = idx >> 5, c4 = idx & 31;
    float4 f = *(const float4*)(v + ((size_t)bh * S + s0 + row) * D + c4 * 4);
    *(float4*)&tile[row][c4 * 4] = f;
  }
  __syncthreads();
#pragma unroll
  for (int i = 0; i < 4; ++i) {
    int c = t + i * 256;              // 1024 chunks (128 d x 8 s-groups)
    int d = c >> 3, s8 = c & 7;
    ushort4 u;
    u.x = f2b(tile[s8 * 4 + 0][d]);
    u.y = f2b(tile[s8 * 4 + 1][d]);
    u.z = f2b(tile[s8 * 4 + 2][d]);
    u.w = f2b(tile[s8 * 4 + 3][d]);
    *(ushort4*)(vtg + ((size_t)bh * D + d) * S + s0 + s8 * 4) = u;
  }
}

// ---------------- kernel 2: dual-stream flash attention, MFMA bf16 ----------------
// grid: (x = bh [32], y = qb [16])  -> same-bh blocks share XCD (id%8) for K/V L2 reuse
__global__ __launch_bounds__(256, 2)
void attn_kernel(const float* __restrict__ q, const float* __restrict__ k,
                 const unsigned short* __restrict__ vtg,
                 float* __restrict__ wsf, float* __restrict__ out) {
  __shared__ unsigned short Ks[32][264];        // 32 keys x 256 d (both streams), +8 pad
  __shared__ unsigned short Vt[128][40];        // 128 d x 32 keys, +8 pad
  __shared__ unsigned short Pa[4][2][32][40];   // [wave][stream][qrow][key]
  __shared__ float sred[4][2];

  const int bh = blockIdx.x, qb = blockIdx.y;
  const int q0 = qb * QTILE;
  const int tid = threadIdx.x;
  const int wave = tid >> 6, lane = tid & 63;
  const int quad = lane >> 4, l16 = lane & 15;
  const float lam = wsf[0];

  // ---- register-resident pre-scaled bf16 Q fragments (A-layout) ----
  short8 qf[2][2][4];                 // [mtile][stream][kstep]
#pragma unroll
  for (int mt = 0; mt < 2; ++mt) {
    int qrow = q0 + wave * 32 + mt * 16 + l16;
    const float* qr = q + ((size_t)bh * S + qrow) * TWOD;
#pragma unroll
    for (int st = 0; st < 2; ++st)
#pragma unroll
      for (int ks = 0; ks < 4; ++ks) {
        const float* p = qr + st * D + ks * 32 + quad * 8;
        float4 f0 = *(const float4*)p;
        float4 f1 = *(const float4*)(p + 4);
        short8 v8;
        v8[0] = (short)f2b(f0.x * SCALE); v8[1] = (short)f2b(f0.y * SCALE);
        v8[2] = (short)f2b(f0.z * SCALE); v8[3] = (short)f2b(f0.w * SCALE);
        v8[4] = (short)f2b(f1.x * SCALE); v8[5] = (short)f2b(f1.y * SCALE);
        v8[6] = (short)f2b(f1.z * SCALE); v8[7] = (short)f2b(f1.w * SCALE);
        qf[mt][st][ks] = v8;
      }
  }

  f32x4 acc[2][2][8];                 // [mtile][stream][d-tile] O accumulators
#pragma unroll
  for (int mt = 0; mt < 2; ++mt)
#pragma unroll
    for (int st = 0; st < 2; ++st)
#pragma unroll
      for (int n = 0; n < 8; ++n) acc[mt][st][n] = (f32x4){0.f, 0.f, 0.f, 0.f};
  float lacc[2][2][4];                // [mtile][stream][reg] running softmax denom (partial)
#pragma unroll
  for (int mt = 0; mt < 2; ++mt)
#pragma unroll
    for (int st = 0; st < 2; ++st)
#pragma unroll
      for (int r = 0; r < 4; ++r) lacc[mt][st][r] = 0.f;

  for (int kt = 0; kt < NKT; ++kt) {
    __syncthreads();                          // prev tile's reads done
    // ---- stage K tile (fp32 -> bf16), coalesced ----
#pragma unroll
    for (int i = 0; i < 8; ++i) {
      int idx = tid + i * 256;                // 2048 f4 chunks = 32 rows x 64
      int row = idx >> 6, c4 = idx & 63;
      float4 f = *(const float4*)(k + ((size_t)bh * S + kt * BC + row) * TWOD + c4 * 4);
      ushort4 u;
      u.x = f2b(f.x); u.y = f2b(f.y); u.z = f2b(f.z); u.w = f2b(f.w);
      *(ushort4*)&Ks[row][c4 * 4] = u;
    }
    // ---- stage V^T tile (already bf16) ----
#pragma unroll
    for (int i = 0; i < 4; ++i) {
      int c = tid + i * 256;                  // 1024 u4 chunks = 128 d x 8
      int d = c >> 3, s8 = c & 7;
      ushort4 u = *(const ushort4*)(vtg + ((size_t)bh * D + d) * S + kt * BC + s8 * 4);
      *(ushort4*)&Vt[d][s8 * 4] = u;
    }
    __syncthreads();                          // staging visible

    // ---- QK^T + exp + P to LDS, per stream ----
#pragma unroll
    for (int st = 0; st < 2; ++st) {
      f32x4 sa[2][2];                         // [mtile][ntile]
#pragma unroll
      for (int mt = 0; mt < 2; ++mt)
#pragma unroll
        for (int nt = 0; nt < 2; ++nt) sa[mt][nt] = (f32x4){0.f, 0.f, 0.f, 0.f};
#pragma unroll
      for (int nt = 0; nt < 2; ++nt)
#pragma unroll
        for (int ks = 0; ks < 4; ++ks) {
          const short8 kf = *(const short8*)&Ks[nt * 16 + l16][st * D + ks * 32 + quad * 8];
          sa[0][nt] = __builtin_amdgcn_mfma_f32_16x16x32_bf16(qf[0][st][ks], kf, sa[0][nt], 0, 0, 0);
          sa[1][nt] = __builtin_amdgcn_mfma_f32_16x16x32_bf16(qf[1][st][ks], kf, sa[1][nt], 0, 0, 0);
        }
      // no-max softmax: p = exp(s); C-layout row = quad*4+reg, col = l16
#pragma unroll
      for (int mt = 0; mt < 2; ++mt)
#pragma unroll
        for (int nt = 0; nt < 2; ++nt)
#pragma unroll
          for (int r = 0; r < 4; ++r) {
            float p = __expf(sa[mt][nt][r]);
            lacc[mt][st][r] += p;
            Pa[wave][st][mt * 16 + quad * 4 + r][nt * 16 + l16] = f2b(p);
          }
    }
    __syncthreads();                          // Pa ready (also orders ds_write->ds_read)

    // ---- P @ V ----
    short8 paf[2][2];
#pragma unroll
    for (int st = 0; st < 2; ++st)
#pragma unroll
      for (int mt = 0; mt < 2; ++mt)
        paf[st][mt] = *(const short8*)&Pa[wave][st][mt * 16 + l16][quad * 8];
#pragma unroll
    for (int nt8 = 0; nt8 < 8; ++nt8) {
      const short8 vf = *(const short8*)&Vt[nt8 * 16 + l16][quad * 8];
#pragma unroll
      for (int st = 0; st < 2; ++st)
#pragma unroll
        for (int mt = 0; mt < 2; ++mt)
          acc[mt][st][nt8] = __builtin_amdgcn_mfma_f32_16x16x32_bf16(paf[st][mt], vf, acc[mt][st][nt8], 0, 0, 0);
    }
  }

  // ---- epilogue: finish softmax denom, combine streams, write pre-GN out ----
#pragma unroll
  for (int mt = 0; mt < 2; ++mt)
#pragma unroll
    for (int st = 0; st < 2; ++st)
#pragma unroll
      for (int r = 0; r < 4; ++r) {
        float v = lacc[mt][st][r];
        v += __shfl_xor(v, 1, 16);
        v += __shfl_xor(v, 2, 16);
        v += __shfl_xor(v, 4, 16);
        v += __shfl_xor(v, 8, 16);
        lacc[mt][st][r] = v;
      }

  float sum = 0.f, ssq = 0.f;
#pragma unroll
  for (int mt = 0; mt < 2; ++mt) {
    float i1[4], i2[4];
#pragma unroll
    for (int r = 0; r < 4; ++r) {
      i1[r] = 1.f / lacc[mt][0][r];
      i2[r] = lam / lacc[mt][1][r];
    }
#pragma unroll
    for (int nt8 = 0; nt8 < 8; ++nt8)
#pragma unroll
      for (int r = 0; r < 4; ++r) {
        float o = acc[mt][0][nt8][r] * i1[r] - acc[mt][1][nt8][r] * i2[r];
        int row = q0 + wave * 32 + mt * 16 + quad * 4 + r;
        out[((size_t)bh * S + row) * D + nt8 * 16 + l16] = o;
        sum += o; ssq += o * o;
      }
  }
  // block-level GN partials
#pragma unroll
  for (int off = 32; off >= 1; off >>= 1) {
    sum += __shfl_xor(sum, off, 64);
    ssq += __shfl_xor(ssq, off, 64);
  }
  if (lane == 0) { sred[wave][0] = sum; sred[wave][1] = ssq; }
  __syncthreads();
  if (tid == 0) {
    float s0 = sred[0][0] + sred[1][0] + sred[2][0] + sred[3][0];
    float s1 = sred[0][1] + sred[1][1] + sred[2][1] + sred[3][1];
    int idx = bh * 16 + qb;
    wsf[64 + idx * 2] = s0;
    wsf[64 + idx * 2 + 1] = s1;
  }
}

// ---------------- kernel 3: group norm (in-place on out) ----------------
// grid (x = bh [32], y = part [8])
__global__ void gn_kernel(float* __restrict__ out, const float* __restrict__ gw,
                          const float* __restrict__ gb, const float* __restrict__ wsf) {
  const int bh = blockIdx.x, part = blockIdx.y;
  const int h = bh & (H - 1);
  float sum = 0.f, ssq = 0.f;
  for (int j = 0; j < 16; ++j) {
    sum += wsf[64 + (bh * 16 + j) * 2];
    ssq += wsf[64 + (bh * 16 + j) * 2 + 1];
  }
  const float invn = 1.f / (float)(S * D);
  const float mean = sum * invn;
  const float var = ssq * invn - mean * mean;
  const float rstd = rsqrtf(var + GN_EPS);
  const float outscale = 1.f - LAM_INIT;
  const float4* g4 = (const float4*)(gw + h * D);
  const float4* b4 = (const float4*)(gb + h * D);
  float4* o4 = (float4*)(out + (size_t)bh * S * D);
  const int chunks_per = (S * D / 4) / 8;   // 8192
  const int c0 = part * chunks_per;
  for (int c = c0 + threadIdx.x; c < c0 + chunks_per; c += 256) {
    float4 vv = o4[c];
    int d4 = c & 31;
    float4 g = g4[d4], bb = b4[d4];
    vv.x = ((vv.x - mean) * rstd * g.x + bb.x) * outscale;
    vv.y = ((vv.y - mean) * rstd * g.y + bb.y) * outscale;
    vv.z = ((vv.z - mean) * rstd * g.z + bb.z) * outscale;
    vv.w = ((vv.w - mean) * rstd * g.w + bb.w) * outscale;
    o4[c] = vv;
  }
}

extern "C" void kernel_launch(void* const* d_in, const int* in_sizes, int n_in,
                              void* d_out, int out_size, void* d_ws, size_t ws_size,
                              hipStream_t stream) {
  (void)in_sizes; (void)n_in; (void)out_size; (void)ws_size;
  const float* q   = (const float*)d_in[0];
  const float* k   = (const float*)d_in[1];
  const float* v   = (const float*)d_in[2];
  const float* lq1 = (const float*)d_in[3];
  const float* lq2 = (const float*)d_in[4];
  const float* lk1 = (const float*)d_in[5];
  const float* lk2 = (const float*)d_in[6];
  const float* gw  = (const float*)d_in[7];
  const float* gb  = (const float*)d_in[8];
  float* out = (float*)d_out;
  float* wsf = (float*)d_ws;                                   // [0]=lam, [64..1088) partials
  unsigned short* vtg = (unsigned short*)((char*)d_ws + 8192); // bf16 V^T, 16.78 MB

  lam_kernel<<<dim3(1), dim3(128), 0, stream>>>(lq1, lq2, lk1, lk2, wsf);
  vt_kernel<<<dim3(S / 32, BH), dim3(256), 0, stream>>>(v, vtg);
  attn_kernel<<<dim3(BH, S / QTILE), dim3(256), 0, stream>>>(q, k, vtg, wsf, out);
  gn_kernel<<<dim3(BH, 8), dim3(256), 0, stream>>>(out, gw, gb, wsf);
}

// Round 2
// 539.606 us; speedup vs baseline: 1.3745x; 1.3745x over previous
//
#include <hip/hip_runtime.h>
#include <cstddef>

constexpr int B = 2, H = 16, S = 2048, D = 128;
constexpr int BH = B * H;
constexpr int TWOD = 2 * D;          // 256
constexpr int QTILE = 128;           // q rows per block: 4 waves x 2 mtiles x 16
constexpr int BC = 32;               // keys per tile
constexpr int NKT = S / BC;          // 64
constexpr float SCALE = 0.08838834764831845f;  // 1/sqrt(128)
constexpr float SC2 = 0.08838834764831845f * 1.4426950408889634f; // SCALE*log2(e)
constexpr float LAM_INIT = 0.8f;
constexpr float GN_EPS = 1e-5f;

typedef __attribute__((ext_vector_type(8))) short short8;
typedef __attribute__((ext_vector_type(4))) float f32x4;

__device__ __forceinline__ unsigned short f2b(float f) {
  unsigned int u = __float_as_uint(f);
  u += 0x7fffu + ((u >> 16) & 1u);
  return (unsigned short)(u >> 16);
}

__device__ __forceinline__ void async_copy16(const void* g, void* l) {
  typedef __attribute__((address_space(1))) const void gvoid;
  typedef __attribute__((address_space(3))) void lvoid;
  __builtin_amdgcn_global_load_lds((gvoid*)g, (lvoid*)l, 16, 0, 0);
}

// ---------------- kernel 0: lambda scalar -> wsf[0] ----------------
__global__ void lam_kernel(const float* __restrict__ lq1, const float* __restrict__ lq2,
                           const float* __restrict__ lk1, const float* __restrict__ lk2,
                           float* __restrict__ wsf) {
  __shared__ float r1[128], r2[128];
  int t = threadIdx.x;
  r1[t] = lq1[t] * lk1[t];
  r2[t] = lq2[t] * lk2[t];
  __syncthreads();
  if (t == 0) {
    float s1 = 0.f, s2 = 0.f;
    for (int i = 0; i < 128; ++i) { s1 += r1[i]; s2 += r2[i]; }
    wsf[0] = expf(s1) - expf(s2) + LAM_INIT;
  }
}

// ---------------- kernel 1: k fp32 -> bf16, same layout ----------------
__global__ void convk_kernel(const float* __restrict__ src, unsigned short* __restrict__ dst) {
  size_t i = ((size_t)blockIdx.x * 256 + threadIdx.x) * 8;
  float4 a = *(const float4*)(src + i);
  float4 b = *(const float4*)(src + i + 4);
  unsigned short u[8];
  u[0] = f2b(a.x); u[1] = f2b(a.y); u[2] = f2b(a.z); u[3] = f2b(a.w);
  u[4] = f2b(b.x); u[5] = f2b(b.y); u[6] = f2b(b.z); u[7] = f2b(b.w);
  *(uint4*)(dst + i) = *(uint4*)u;
}

// ---------------- kernel 2: v [bh][s][d] fp32 -> vt [bh][d][s] bf16 ----------------
__global__ void vt_kernel(const float* __restrict__ v, unsigned short* __restrict__ vtg) {
  __shared__ float tile[32][132];
  const int bh = blockIdx.y, s0 = blockIdx.x * 32, t = threadIdx.x;
#pragma unroll
  for (int i = 0; i < 4; ++i) {
    int idx = t + i * 256;
    int row = idx >> 5, c4 = idx & 31;
    float4 f = *(const float4*)(v + ((size_t)bh * S + s0 + row) * D + c4 * 4);
    *(float4*)&tile[row][c4 * 4] = f;
  }
  __syncthreads();
#pragma unroll
  for (int i = 0; i < 4; ++i) {
    int c = t + i * 256;
    int d = c >> 3, s8 = c & 7;
    ushort4 u;
    u.x = f2b(tile[s8 * 4 + 0][d]);
    u.y = f2b(tile[s8 * 4 + 1][d]);
    u.z = f2b(tile[s8 * 4 + 2][d]);
    u.w = f2b(tile[s8 * 4 + 3][d]);
    *(ushort4*)(vtg + ((size_t)bh * D + d) * S + s0 + s8 * 4) = u;
  }
}

// ---------------- kernel 3: dual-stream flash attention ----------------
// Double-buffered async K staging (global_load_lds w16, XOR(row&7) 16B-chunk
// swizzle for conflict-free B-frag reads), VGPR-staged V, wave-private Pa
// round-trip (no mid-loop barrier). 1 barrier per K-tile.
__global__ __launch_bounds__(256, 2)
void attn_kernel(const float* __restrict__ q, const unsigned short* __restrict__ kbf,
                 const unsigned short* __restrict__ vtg,
                 float* __restrict__ wsf, float* __restrict__ out) {
  __shared__ unsigned short Ks[2][32][256];     // unpadded (async dest); swizzled chunks
  __shared__ unsigned short Vt[2][128][40];     // pitch 40 (80B, 16B-aligned, 2-way max)
  __shared__ unsigned short Pa[4][2][32][40];   // wave-private P tiles
  __shared__ float sred[4][2];

  const int bh = blockIdx.x, qb = blockIdx.y;
  const int q0 = qb * QTILE;
  const int tid = threadIdx.x;
  const int wave = tid >> 6, lane = tid & 63;
  const int quad = lane >> 4, l16 = lane & 15;
  const float lam = wsf[0];

  // ---- register-resident bf16 Q fragments (unscaled; SCALE folded into exp2) ----
  short8 qf[2][2][4];
#pragma unroll
  for (int mt = 0; mt < 2; ++mt) {
    int qrow = q0 + wave * 32 + mt * 16 + l16;
    const float* qr = q + ((size_t)bh * S + qrow) * TWOD;
#pragma unroll
    for (int st = 0; st < 2; ++st)
#pragma unroll
      for (int ks = 0; ks < 4; ++ks) {
        const float* p = qr + st * D + ks * 32 + quad * 8;
        float4 f0 = *(const float4*)p;
        float4 f1 = *(const float4*)(p + 4);
        short8 v8;
        v8[0] = (short)f2b(f0.x); v8[1] = (short)f2b(f0.y);
        v8[2] = (short)f2b(f0.z); v8[3] = (short)f2b(f0.w);
        v8[4] = (short)f2b(f1.x); v8[5] = (short)f2b(f1.y);
        v8[6] = (short)f2b(f1.z); v8[7] = (short)f2b(f1.w);
        qf[mt][st][ks] = v8;
      }
  }

  // ---- staging address precompute ----
  const unsigned short* kbase = kbf + (size_t)bh * S * (size_t)TWOD;
  int goff[4];                       // ushort offset within a K tile, per issue
#pragma unroll
  for (int i = 0; i < 4; ++i) {
    int L = i * 256 + tid;           // lds 16B-chunk index
    int row = L >> 5, cp = L & 31;
    int g = cp ^ (row & 7);          // fetch swizzled source chunk
    goff[i] = row * 256 + g * 8;
  }
  const unsigned short* vbase = vtg + (size_t)bh * D * (size_t)S;
  const int vd0 = tid >> 2, vcp = tid & 3;   // V chunk: rows vd0 and vd0+64

  f32x4 acc[2][2][8];
#pragma unroll
  for (int mt = 0; mt < 2; ++mt)
#pragma unroll
    for (int st = 0; st < 2; ++st)
#pragma unroll
      for (int n = 0; n < 8; ++n) acc[mt][st][n] = (f32x4){0.f, 0.f, 0.f, 0.f};
  float lacc[2][2][4];
#pragma unroll
  for (int mt = 0; mt < 2; ++mt)
#pragma unroll
    for (int st = 0; st < 2; ++st)
#pragma unroll
      for (int r = 0; r < 4; ++r) lacc[mt][st][r] = 0.f;

  // ---- prologue: stage tile 0 into buffer 0 ----
  {
    uint4 v0 = *(const uint4*)(vbase + (size_t)vd0 * S + vcp * 8);
    uint4 v1 = *(const uint4*)(vbase + (size_t)(vd0 + 64) * S + vcp * 8);
#pragma unroll
    for (int i = 0; i < 4; ++i)
      async_copy16(kbase + goff[i], &Ks[0][0][0] + (i * 256 + tid) * 8);
    *(uint4*)&Vt[0][vd0][vcp * 8] = v0;
    *(uint4*)&Vt[0][vd0 + 64][vcp * 8] = v1;
  }
  __syncthreads();

  int cur = 0;
  for (int kt = 0; kt < NKT; ++kt) {
    const bool pre = (kt + 1 < NKT);
    uint4 vr0, vr1;
    if (pre) {
      const unsigned short* vp = vbase + (kt + 1) * BC + vcp * 8;
      vr0 = *(const uint4*)(vp + (size_t)vd0 * S);
      vr1 = *(const uint4*)(vp + (size_t)(vd0 + 64) * S);
      const unsigned short* kp = kbase + (size_t)(kt + 1) * BC * TWOD;
      unsigned short* ldsb = &Ks[cur ^ 1][0][0];
#pragma unroll
      for (int i = 0; i < 4; ++i)
        async_copy16(kp + goff[i], ldsb + (i * 256 + tid) * 8);
    }

    // ---- QK^T + exp + P to wave-private LDS ----
#pragma unroll
    for (int st = 0; st < 2; ++st) {
      f32x4 sa[2][2];
#pragma unroll
      for (int mt = 0; mt < 2; ++mt)
#pragma unroll
        for (int nt = 0; nt < 2; ++nt) sa[mt][nt] = (f32x4){0.f, 0.f, 0.f, 0.f};
#pragma unroll
      for (int nt = 0; nt < 2; ++nt) {
        const int row = nt * 16 + l16;
        const int rx = row & 7;
#pragma unroll
        for (int ks = 0; ks < 4; ++ks) {
          const int pos = (st * 16 + ks * 4 + quad) ^ rx;
          const short8 kf = *(const short8*)&Ks[cur][row][pos * 8];
          sa[0][nt] = __builtin_amdgcn_mfma_f32_16x16x32_bf16(qf[0][st][ks], kf, sa[0][nt], 0, 0, 0);
          sa[1][nt] = __builtin_amdgcn_mfma_f32_16x16x32_bf16(qf[1][st][ks], kf, sa[1][nt], 0, 0, 0);
        }
      }
#pragma unroll
      for (int mt = 0; mt < 2; ++mt)
#pragma unroll
        for (int nt = 0; nt < 2; ++nt)
#pragma unroll
          for (int r = 0; r < 4; ++r) {
            float p = __builtin_amdgcn_exp2f(sa[mt][nt][r] * SC2);
            lacc[mt][st][r] += p;
            Pa[wave][st][mt * 16 + quad * 4 + r][nt * 16 + l16] = f2b(p);
          }
    }

    if (pre) {   // V regs -> next buffer (loads had the whole QK phase to land)
      *(uint4*)&Vt[cur ^ 1][vd0][vcp * 8] = vr0;
      *(uint4*)&Vt[cur ^ 1][vd0 + 64][vcp * 8] = vr1;
    }

    // ---- P @ V (wave-private Pa: lgkmcnt ordering, no barrier needed) ----
    short8 paf[2][2];
#pragma unroll
    for (int st = 0; st < 2; ++st)
#pragma unroll
      for (int mt = 0; mt < 2; ++mt)
        paf[st][mt] = *(const short8*)&Pa[wave][st][mt * 16 + l16][quad * 8];
#pragma unroll
    for (int nt8 = 0; nt8 < 8; ++nt8) {
      const short8 vf = *(const short8*)&Vt[cur][nt8 * 16 + l16][quad * 8];
#pragma unroll
      for (int st = 0; st < 2; ++st)
#pragma unroll
        for (int mt = 0; mt < 2; ++mt)
          acc[mt][st][nt8] = __builtin_amdgcn_mfma_f32_16x16x32_bf16(paf[st][mt], vf, acc[mt][st][nt8], 0, 0, 0);
    }

    __syncthreads();   // single barrier: drains next-tile asyncs, fences buffer reuse
    cur ^= 1;
  }

  // ---- epilogue ----
#pragma unroll
  for (int mt = 0; mt < 2; ++mt)
#pragma unroll
    for (int st = 0; st < 2; ++st)
#pragma unroll
      for (int r = 0; r < 4; ++r) {
        float v = lacc[mt][st][r];
        v += __shfl_xor(v, 1, 16);
        v += __shfl_xor(v, 2, 16);
        v += __shfl_xor(v, 4, 16);
        v += __shfl_xor(v, 8, 16);
        lacc[mt][st][r] = v;
      }

  float sum = 0.f, ssq = 0.f;
#pragma unroll
  for (int mt = 0; mt < 2; ++mt) {
    float i1[4], i2[4];
#pragma unroll
    for (int r = 0; r < 4; ++r) {
      i1[r] = 1.f / lacc[mt][0][r];
      i2[r] = lam / lacc[mt][1][r];
    }
#pragma unroll
    for (int nt8 = 0; nt8 < 8; ++nt8)
#pragma unroll
      for (int r = 0; r < 4; ++r) {
        float o = acc[mt][0][nt8][r] * i1[r] - acc[mt][1][nt8][r] * i2[r];
        int row = q0 + wave * 32 + mt * 16 + quad * 4 + r;
        out[((size_t)bh * S + row) * D + nt8 * 16 + l16] = o;
        sum += o; ssq += o * o;
      }
  }
#pragma unroll
  for (int off = 32; off >= 1; off >>= 1) {
    sum += __shfl_xor(sum, off, 64);
    ssq += __shfl_xor(ssq, off, 64);
  }
  if (lane == 0) { sred[wave][0] = sum; sred[wave][1] = ssq; }
  __syncthreads();
  if (tid == 0) {
    float s0 = sred[0][0] + sred[1][0] + sred[2][0] + sred[3][0];
    float s1 = sred[0][1] + sred[1][1] + sred[2][1] + sred[3][1];
    int idx = bh * 16 + qb;
    wsf[64 + idx * 2] = s0;
    wsf[64 + idx * 2 + 1] = s1;
  }
}

// ---------------- kernel 4: group norm (in-place on out) ----------------
__global__ void gn_kernel(float* __restrict__ out, const float* __restrict__ gw,
                          const float* __restrict__ gb, const float* __restrict__ wsf) {
  const int bh = blockIdx.x, part = blockIdx.y;
  const int h = bh & (H - 1);
  float sum = 0.f, ssq = 0.f;
  for (int j = 0; j < 16; ++j) {
    sum += wsf[64 + (bh * 16 + j) * 2];
    ssq += wsf[64 + (bh * 16 + j) * 2 + 1];
  }
  const float invn = 1.f / (float)(S * D);
  const float mean = sum * invn;
  const float var = ssq * invn - mean * mean;
  const float rstd = rsqrtf(var + GN_EPS);
  const float outscale = 1.f - LAM_INIT;
  const float4* g4 = (const float4*)(gw + h * D);
  const float4* b4 = (const float4*)(gb + h * D);
  float4* o4 = (float4*)(out + (size_t)bh * S * D);
  const int chunks_per = (S * D / 4) / 8;
  const int c0 = part * chunks_per;
  for (int c = c0 + threadIdx.x; c < c0 + chunks_per; c += 256) {
    float4 vv = o4[c];
    int d4 = c & 31;
    float4 g = g4[d4], bb = b4[d4];
    vv.x = ((vv.x - mean) * rstd * g.x + bb.x) * outscale;
    vv.y = ((vv.y - mean) * rstd * g.y + bb.y) * outscale;
    vv.z = ((vv.z - mean) * rstd * g.z + bb.z) * outscale;
    vv.w = ((vv.w - mean) * rstd * g.w + bb.w) * outscale;
    o4[c] = vv;
  }
}

extern "C" void kernel_launch(void* const* d_in, const int* in_sizes, int n_in,
                              void* d_out, int out_size, void* d_ws, size_t ws_size,
                              hipStream_t stream) {
  (void)in_sizes; (void)n_in; (void)out_size; (void)ws_size;
  const float* q   = (const float*)d_in[0];
  const float* k   = (const float*)d_in[1];
  const float* v   = (const float*)d_in[2];
  const float* lq1 = (const float*)d_in[3];
  const float* lq2 = (const float*)d_in[4];
  const float* lk1 = (const float*)d_in[5];
  const float* lk2 = (const float*)d_in[6];
  const float* gw  = (const float*)d_in[7];
  const float* gb  = (const float*)d_in[8];
  float* out = (float*)d_out;
  // ws layout: [0,8KB) float scratch (lam + GN partials)
  //            [8KB, +16.78MB) vtg bf16 V^T   [then +33.55MB) kbf bf16 K
  float* wsf = (float*)d_ws;
  unsigned short* vtg = (unsigned short*)((char*)d_ws + 8192);
  unsigned short* kbf = (unsigned short*)((char*)d_ws + 8192 + (size_t)BH * D * S * 2);

  lam_kernel<<<dim3(1), dim3(128), 0, stream>>>(lq1, lq2, lk1, lk2, wsf);
  convk_kernel<<<dim3(BH * S * TWOD / 2048), dim3(256), 0, stream>>>(k, kbf);
  vt_kernel<<<dim3(S / 32, BH), dim3(256), 0, stream>>>(v, vtg);
  attn_kernel<<<dim3(BH, S / QTILE), dim3(256), 0, stream>>>(q, kbf, vtg, wsf, out);
  gn_kernel<<<dim3(BH, 8), dim3(256), 0, stream>>>(out, gw, gb, wsf);
}

// Round 3
// 401.219 us; speedup vs baseline: 1.8486x; 1.3449x over previous
//
#include <hip/hip_runtime.h>
#include <cstddef>

constexpr int B = 2, H = 16, S = 2048, D = 128;
constexpr int BH = B * H;
constexpr int TWOD = 2 * D;          // 256
constexpr int QTILE = 128;           // q rows per block: 4 waves x 2 mtiles x 16
constexpr int BC = 32;               // keys per tile
constexpr int NKT = S / BC;          // 64
constexpr float SC2 = 0.08838834764831845f * 1.4426950408889634f; // (1/sqrt(128))*log2(e)
constexpr float LAM_INIT = 0.8f;
constexpr float GN_EPS = 1e-5f;

typedef __attribute__((ext_vector_type(8))) short short8;
typedef __attribute__((ext_vector_type(4))) float f32x4;

__device__ __forceinline__ unsigned short f2b(float f) {
  unsigned int u = __float_as_uint(f);
  u += 0x7fffu + ((u >> 16) & 1u);
  return (unsigned short)(u >> 16);
}

__device__ __forceinline__ void async_copy16(const void* g, void* l) {
  typedef __attribute__((address_space(1))) const void gvoid;
  typedef __attribute__((address_space(3))) void lvoid;
  __builtin_amdgcn_global_load_lds((gvoid*)g, (lvoid*)l, 16, 0, 0);
}

// ---------------- kernel 0: lambda scalar -> wsf[0] ----------------
__global__ void lam_kernel(const float* __restrict__ lq1, const float* __restrict__ lq2,
                           const float* __restrict__ lk1, const float* __restrict__ lk2,
                           float* __restrict__ wsf) {
  __shared__ float r1[128], r2[128];
  int t = threadIdx.x;
  r1[t] = lq1[t] * lk1[t];
  r2[t] = lq2[t] * lk2[t];
  __syncthreads();
  if (t == 0) {
    float s1 = 0.f, s2 = 0.f;
    for (int i = 0; i < 128; ++i) { s1 += r1[i]; s2 += r2[i]; }
    wsf[0] = expf(s1) - expf(s2) + LAM_INIT;
  }
}

// ---------------- kernel 1: k fp32 -> bf16, same layout ----------------
__global__ void convk_kernel(const float* __restrict__ src, unsigned short* __restrict__ dst) {
  size_t i = ((size_t)blockIdx.x * 256 + threadIdx.x) * 8;
  float4 a = *(const float4*)(src + i);
  float4 b = *(const float4*)(src + i + 4);
  unsigned short u[8];
  u[0] = f2b(a.x); u[1] = f2b(a.y); u[2] = f2b(a.z); u[3] = f2b(a.w);
  u[4] = f2b(b.x); u[5] = f2b(b.y); u[6] = f2b(b.z); u[7] = f2b(b.w);
  *(uint4*)(dst + i) = *(uint4*)u;
}

// ---------------- kernel 2: v [bh][s][d] fp32 -> vt [bh][d][s] bf16 ----------------
// 64s x 128d tiles; writes are 128B-contiguous segments (8 threads x 16B).
__global__ void vt_kernel(const float* __restrict__ v, unsigned short* __restrict__ vtg) {
  __shared__ float tile[64][129];     // pitch 129 words: column reads <=2-way
  const int bh = blockIdx.y, s0 = blockIdx.x * 64, t = threadIdx.x;
#pragma unroll
  for (int i = 0; i < 8; ++i) {
    int idx = t + i * 256;            // 2048 f4 chunks (64 s x 32 f4)
    int row = idx >> 5, c4 = idx & 31;
    float4 f = *(const float4*)(v + ((size_t)bh * S + s0 + row) * D + c4 * 4);
    tile[row][c4 * 4 + 0] = f.x; tile[row][c4 * 4 + 1] = f.y;
    tile[row][c4 * 4 + 2] = f.z; tile[row][c4 * 4 + 3] = f.w;
  }
  __syncthreads();
#pragma unroll
  for (int i = 0; i < 4; ++i) {
    int c = t + i * 256;              // 1024 chunks (128 d x 8 k-groups)
    int d = c >> 3, k8 = c & 7;
    unsigned short u[8];
#pragma unroll
    for (int j = 0; j < 8; ++j) u[j] = f2b(tile[k8 * 8 + j][d]);
    *(uint4*)(vtg + ((size_t)bh * D + d) * S + s0 + k8 * 8) = *(uint4*)u;
  }
}

// ---------------- kernel 3: dual-stream flash attention, pipelined ----------------
// PV(t-1) overlaps QK(t): paf/vf read at iter top, PV MFMAs independent of
// QK(t) -> fills exp/LDS-wait stalls. Single wave-private Pa buffer (per-wave
// in-order DS ops make read-P(t-1)-then-write-P(t) safe). Pa chunk-XOR swizzle
// kills the 4-way scalar-write conflicts. 1 barrier/iter.
__global__ __launch_bounds__(256, 2)
void attn_kernel(const float* __restrict__ q, const unsigned short* __restrict__ kbf,
                 const unsigned short* __restrict__ vtg,
                 float* __restrict__ wsf, float* __restrict__ out) {
  __shared__ __attribute__((aligned(16))) unsigned short Ks[2][32][256];  // async dest, chunk-swizzled
  __shared__ __attribute__((aligned(16))) unsigned short Vt[2][128][40];  // pitch 40
  __shared__ __attribute__((aligned(16))) unsigned short Pa[4][2][32][40];// wave-private, swizzled
  __shared__ float sred[4][2];

  const int bh = blockIdx.x, qb = blockIdx.y;
  const int q0 = qb * QTILE;
  const int tid = threadIdx.x;
  const int wave = tid >> 6, lane = tid & 63;
  const int quad = lane >> 4, l16 = lane & 15;
  const float lam = wsf[0];

  // ---- register-resident bf16 Q fragments (A-layout) ----
  short8 qf[2][2][4];                 // [mtile][stream][kstep]
#pragma unroll
  for (int mt = 0; mt < 2; ++mt) {
    int qrow = q0 + wave * 32 + mt * 16 + l16;
    const float* qr = q + ((size_t)bh * S + qrow) * TWOD;
#pragma unroll
    for (int st = 0; st < 2; ++st)
#pragma unroll
      for (int ks = 0; ks < 4; ++ks) {
        const float* p = qr + st * D + ks * 32 + quad * 8;
        float4 f0 = *(const float4*)p;
        float4 f1 = *(const float4*)(p + 4);
        short8 v8;
        v8[0] = (short)f2b(f0.x); v8[1] = (short)f2b(f0.y);
        v8[2] = (short)f2b(f0.z); v8[3] = (short)f2b(f0.w);
        v8[4] = (short)f2b(f1.x); v8[5] = (short)f2b(f1.y);
        v8[6] = (short)f2b(f1.z); v8[7] = (short)f2b(f1.w);
        qf[mt][st][ks] = v8;
      }
  }

  // ---- staging addresses ----
  const unsigned short* kbase = kbf + (size_t)bh * S * (size_t)TWOD;
  int goff[4];
#pragma unroll
  for (int i = 0; i < 4; ++i) {
    int L = i * 256 + tid;
    int row = L >> 5, cp = L & 31;
    int g = cp ^ (row & 7);
    goff[i] = row * 256 + g * 8;
  }
  const unsigned short* vbase = vtg + (size_t)bh * D * (size_t)S;
  const int vd0 = tid >> 2, vcp = tid & 3;

  f32x4 acc[2][2][8];
#pragma unroll
  for (int mt = 0; mt < 2; ++mt)
#pragma unroll
    for (int st = 0; st < 2; ++st)
#pragma unroll
      for (int n = 0; n < 8; ++n) acc[mt][st][n] = (f32x4){0.f, 0.f, 0.f, 0.f};
  float lacc[2][2][4];
#pragma unroll
  for (int mt = 0; mt < 2; ++mt)
#pragma unroll
    for (int st = 0; st < 2; ++st)
#pragma unroll
      for (int r = 0; r < 4; ++r) lacc[mt][st][r] = 0.f;

  // Pa read/write index helpers (chunk-XOR swizzle, pitch 40):
  //   physical_chunk = logical_chunk ^ ((row>>2)&3)
  const int pa_rd_off = (quad ^ ((l16 >> 2) & 3)) * 8;   // read: row=mt*16+l16, chunk=quad

  // ---- QK / exp+Pwrite / PV as lambdas ----
  auto qk = [&](int st, int kb, f32x4 (&sa)[2][2]) {
#pragma unroll
    for (int nt = 0; nt < 2; ++nt) {
      const int row = nt * 16 + l16;
      const int rx = row & 7;
#pragma unroll
      for (int ks = 0; ks < 4; ++ks) {
        const int pos = (st * 16 + ks * 4 + quad) ^ rx;
        const short8 kf = *(const short8*)&Ks[kb][row][pos * 8];
        sa[0][nt] = __builtin_amdgcn_mfma_f32_16x16x32_bf16(qf[0][st][ks], kf, sa[0][nt], 0, 0, 0);
        sa[1][nt] = __builtin_amdgcn_mfma_f32_16x16x32_bf16(qf[1][st][ks], kf, sa[1][nt], 0, 0, 0);
      }
    }
  };
  auto pexp = [&](int st, f32x4 (&sa)[2][2]) {
#pragma unroll
    for (int mt = 0; mt < 2; ++mt)
#pragma unroll
      for (int nt = 0; nt < 2; ++nt)
#pragma unroll
        for (int r = 0; r < 4; ++r) {
          float p = __builtin_amdgcn_exp2f(sa[mt][nt][r] * SC2);
          lacc[mt][st][r] += p;
          int colp = (((nt * 2) + (l16 >> 3)) ^ quad) * 8 + (l16 & 7);
          Pa[wave][st][mt * 16 + quad * 4 + r][colp] = f2b(p);
        }
  };
  auto pv = [&](int st, const short8 (&paf)[2], const short8 (&vf)[8]) {
#pragma unroll
    for (int nt8 = 0; nt8 < 8; ++nt8)
#pragma unroll
      for (int mt = 0; mt < 2; ++mt)
        acc[mt][st][nt8] = __builtin_amdgcn_mfma_f32_16x16x32_bf16(paf[mt], vf[nt8], acc[mt][st][nt8], 0, 0, 0);
  };

  // ---- prologue: zero Pa + Vt[1] (so PV(-1) adds exact zeros), stage tile 0 ----
  {
    const uint4 z = {0u, 0u, 0u, 0u};
    unsigned short* pz = &Pa[0][0][0][0];
    for (int i = tid; i < 1280; i += 256) *(uint4*)(pz + i * 8) = z;  // 20480 B
    unsigned short* vz = &Vt[1][0][0];
    for (int i = tid; i < 640; i += 256) *(uint4*)(vz + i * 8) = z;   // 10240 B
#pragma unroll
    for (int i = 0; i < 4; ++i)
      async_copy16(kbase + goff[i], &Ks[0][0][0] + (i * 256 + tid) * 8);
    uint4 v0 = *(const uint4*)(vbase + (size_t)vd0 * S + vcp * 8);
    uint4 v1 = *(const uint4*)(vbase + (size_t)(vd0 + 64) * S + vcp * 8);
    *(uint4*)&Vt[0][vd0][vcp * 8] = v0;
    *(uint4*)&Vt[0][vd0 + 64][vcp * 8] = v1;
  }
  __syncthreads();

  for (int t = 0; t < NKT; ++t) {
    const int kbuf = t & 1;
    const int pvbuf = kbuf ^ 1;      // holds V(t-1); also target for K(t+1)/V(t+1)

    // ---- top-of-iter LDS reads: P(t-1) A-frags + V(t-1) B-frags ----
    short8 paf[2][2], vf[8];
#pragma unroll
    for (int st = 0; st < 2; ++st)
#pragma unroll
      for (int mt = 0; mt < 2; ++mt)
        paf[st][mt] = *(const short8*)&Pa[wave][st][mt * 16 + l16][pa_rd_off];
#pragma unroll
    for (int nt8 = 0; nt8 < 8; ++nt8)
      vf[nt8] = *(const short8*)&Vt[pvbuf][nt8 * 16 + l16][quad * 8];

    // ---- prefetch tile t+1 ----
    const bool pre = (t + 1 < NKT);
    uint4 vr0, vr1;
    if (pre) {
      const unsigned short* vp = vbase + (t + 1) * BC + vcp * 8;
      vr0 = *(const uint4*)(vp + (size_t)vd0 * S);
      vr1 = *(const uint4*)(vp + (size_t)(vd0 + 64) * S);
      const unsigned short* kp = kbase + (size_t)(t + 1) * BC * TWOD;
      unsigned short* ldsb = &Ks[pvbuf][0][0];
#pragma unroll
      for (int i = 0; i < 4; ++i)
        async_copy16(kp + goff[i], ldsb + (i * 256 + tid) * 8);
    }

    // ---- pipelined compute: QK(t) interleaved with PV(t-1) ----
    f32x4 sa0[2][2], sa1[2][2];
#pragma unroll
    for (int mt = 0; mt < 2; ++mt)
#pragma unroll
      for (int nt = 0; nt < 2; ++nt) {
        sa0[mt][nt] = (f32x4){0.f, 0.f, 0.f, 0.f};
        sa1[mt][nt] = (f32x4){0.f, 0.f, 0.f, 0.f};
      }
    qk(0, kbuf, sa0);
    pv(0, paf[0], vf);
    pexp(0, sa0);
    qk(1, kbuf, sa1);
    pv(1, paf[1], vf);
    pexp(1, sa1);

    __syncthreads();                 // drains K(t+1) DMA; fences Ks/Vt buffer reuse
    if (pre) {                       // V(t+1) -> Vt[pvbuf] (all PV(t-1) reads done)
      *(uint4*)&Vt[pvbuf][vd0][vcp * 8] = vr0;
      *(uint4*)&Vt[pvbuf][vd0 + 64][vcp * 8] = vr1;
    }
  }

  // ---- epilogue PV(NKT-1): P in Pa, V(NKT-1) in Vt[(NKT-1)&1] = Vt[1] ----
  {
    short8 paf[2][2], vf[8];
#pragma unroll
    for (int st = 0; st < 2; ++st)
#pragma unroll
      for (int mt = 0; mt < 2; ++mt)
        paf[st][mt] = *(const short8*)&Pa[wave][st][mt * 16 + l16][pa_rd_off];
#pragma unroll
    for (int nt8 = 0; nt8 < 8; ++nt8)
      vf[nt8] = *(const short8*)&Vt[1][nt8 * 16 + l16][quad * 8];
    pv(0, paf[0], vf);
    pv(1, paf[1], vf);
  }

  // ---- softmax denominators ----
#pragma unroll
  for (int mt = 0; mt < 2; ++mt)
#pragma unroll
    for (int st = 0; st < 2; ++st)
#pragma unroll
      for (int r = 0; r < 4; ++r) {
        float v = lacc[mt][st][r];
        v += __shfl_xor(v, 1, 16);
        v += __shfl_xor(v, 2, 16);
        v += __shfl_xor(v, 4, 16);
        v += __shfl_xor(v, 8, 16);
        lacc[mt][st][r] = v;
      }

  float sum = 0.f, ssq = 0.f;
#pragma unroll
  for (int mt = 0; mt < 2; ++mt) {
    float i1[4], i2[4];
#pragma unroll
    for (int r = 0; r < 4; ++r) {
      i1[r] = 1.f / lacc[mt][0][r];
      i2[r] = lam / lacc[mt][1][r];
    }
#pragma unroll
    for (int nt8 = 0; nt8 < 8; ++nt8)
#pragma unroll
      for (int r = 0; r < 4; ++r) {
        float o = acc[mt][0][nt8][r] * i1[r] - acc[mt][1][nt8][r] * i2[r];
        int row = q0 + wave * 32 + mt * 16 + quad * 4 + r;
        out[((size_t)bh * S + row) * D + nt8 * 16 + l16] = o;
        sum += o; ssq += o * o;
      }
  }
#pragma unroll
  for (int off = 32; off >= 1; off >>= 1) {
    sum += __shfl_xor(sum, off, 64);
    ssq += __shfl_xor(ssq, off, 64);
  }
  if (lane == 0) { sred[wave][0] = sum; sred[wave][1] = ssq; }
  __syncthreads();
  if (tid == 0) {
    float s0 = sred[0][0] + sred[1][0] + sred[2][0] + sred[3][0];
    float s1 = sred[0][1] + sred[1][1] + sred[2][1] + sred[3][1];
    int idx = bh * 16 + qb;
    wsf[64 + idx * 2] = s0;
    wsf[64 + idx * 2 + 1] = s1;
  }
}

// ---------------- kernel 4: group norm (in-place on out) ----------------
__global__ void gn_kernel(float* __restrict__ out, const float* __restrict__ gw,
                          const float* __restrict__ gb, const float* __restrict__ wsf) {
  const int bh = blockIdx.x, part = blockIdx.y;
  const int h = bh & (H - 1);
  float sum = 0.f, ssq = 0.f;
  for (int j = 0; j < 16; ++j) {
    sum += wsf[64 + (bh * 16 + j) * 2];
    ssq += wsf[64 + (bh * 16 + j) * 2 + 1];
  }
  const float invn = 1.f / (float)(S * D);
  const float mean = sum * invn;
  const float var = ssq * invn - mean * mean;
  const float rstd = rsqrtf(var + GN_EPS);
  const float outscale = 1.f - LAM_INIT;
  const float4* g4 = (const float4*)(gw + h * D);
  const float4* b4 = (const float4*)(gb + h * D);
  float4* o4 = (float4*)(out + (size_t)bh * S * D);
  const int chunks_per = (S * D / 4) / 8;
  const int c0 = part * chunks_per;
  for (int c = c0 + threadIdx.x; c < c0 + chunks_per; c += 256) {
    float4 vv = o4[c];
    int d4 = c & 31;
    float4 g = g4[d4], bb = b4[d4];
    vv.x = ((vv.x - mean) * rstd * g.x + bb.x) * outscale;
    vv.y = ((vv.y - mean) * rstd * g.y + bb.y) * outscale;
    vv.z = ((vv.z - mean) * rstd * g.z + bb.z) * outscale;
    vv.w = ((vv.w - mean) * rstd * g.w + bb.w) * outscale;
    o4[c] = vv;
  }
}

extern "C" void kernel_launch(void* const* d_in, const int* in_sizes, int n_in,
                              void* d_out, int out_size, void* d_ws, size_t ws_size,
                              hipStream_t stream) {
  (void)in_sizes; (void)n_in; (void)out_size; (void)ws_size;
  const float* q   = (const float*)d_in[0];
  const float* k   = (const float*)d_in[1];
  const float* v   = (const float*)d_in[2];
  const float* lq1 = (const float*)d_in[3];
  const float* lq2 = (const float*)d_in[4];
  const float* lk1 = (const float*)d_in[5];
  const float* lk2 = (const float*)d_in[6];
  const float* gw  = (const float*)d_in[7];
  const float* gb  = (const float*)d_in[8];
  float* out = (float*)d_out;
  float* wsf = (float*)d_ws;
  unsigned short* vtg = (unsigned short*)((char*)d_ws + 8192);
  unsigned short* kbf = (unsigned short*)((char*)d_ws + 8192 + (size_t)BH * D * S * 2);

  lam_kernel<<<dim3(1), dim3(128), 0, stream>>>(lq1, lq2, lk1, lk2, wsf);
  convk_kernel<<<dim3(BH * S * TWOD / 2048), dim3(256), 0, stream>>>(k, kbf);
  vt_kernel<<<dim3(S / 64, BH), dim3(256), 0, stream>>>(v, vtg);
  attn_kernel<<<dim3(BH, S / QTILE), dim3(256), 0, stream>>>(q, kbf, vtg, wsf, out);
  gn_kernel<<<dim3(BH, 8), dim3(256), 0, stream>>>(out, gw, gb, wsf);
}